// Round 6
// baseline (342.458 us; speedup 1.0000x reference)
//
#include <hip/hip_runtime.h>

#define C_DIM 256
#define K_DIM 128
#define HW_DIM 64
#define PIX 4096
#define N_IMG 32

using short8 = __attribute__((ext_vector_type(8))) short;
using f32x4  = __attribute__((ext_vector_type(4))) float;

__device__ __forceinline__ unsigned long long umin64(unsigned long long a, unsigned long long b) {
    return a < b ? a : b;
}
__device__ __forceinline__ unsigned mono(float d) {
    unsigned u = __float_as_uint(d);
    return u ^ ((u & 0x80000000u) ? 0xFFFFFFFFu : 0x80000000u);
}

// Truncation split: v = hi + mid + lo, each term = top-16-bit bitmask value
// (exact Sterbenz residuals; lo ~ 2^-16 * v). Cheap: and/sub only.
__device__ __forceinline__ void split3t(float v, unsigned& hu, unsigned& mu, unsigned& lu) {
    unsigned u = __float_as_uint(v);
    unsigned hf = u & 0xffff0000u;
    float r1 = v - __uint_as_float(hf);
    unsigned r1u = __float_as_uint(r1);
    unsigned mf = r1u & 0xffff0000u;
    float r2 = r1 - __uint_as_float(mf);
    hu = u; mu = r1u; lu = __float_as_uint(r2);   // consumers take >>16
}

// P: per cluster k: trunc 3-way split -> Bt[k][768] (planes hi/mid/lo) + exact c2
__global__ __launch_bounds__(64) void prep_kernel(const float* __restrict__ cl,
                                                  unsigned short* __restrict__ Bt,
                                                  float* __restrict__ c2) {
    int k = blockIdx.x;
    int lane = threadIdx.x;
    const float4* row = (const float4*)(cl + k * C_DIM);
    float4 v = row[lane];
    float vv[4] = {v.x, v.y, v.z, v.w};
    unsigned short* bk = Bt + k * 768 + lane * 4;
#pragma unroll
    for (int i = 0; i < 4; ++i) {
        unsigned hu, mu, lu;
        split3t(vv[i], hu, mu, lu);
        bk[i]       = (unsigned short)(hu >> 16);
        bk[256 + i] = (unsigned short)(mu >> 16);
        bk[512 + i] = (unsigned short)(lu >> 16);
    }
    if (lane == 0) {   // identical op order to proven-exact c2
        float s = 0.f;
#pragma unroll
    for (int i = 0; i < C_DIM / 4; ++i) {
            float4 u = row[i];
            s = fmaf(u.x, u.x, s);
            s = fmaf(u.y, u.y, s);
            s = fmaf(u.z, u.z, s);
            s = fmaf(u.w, u.w, s);
        }
        c2[k] = s;
    }
}

// Main, ROUND-NEW structure: BARRIER-FREE m-split with REGISTER-DIRECT A.
// Each wave owns 16 px x ALL 128 clusters. Converter lane L = (g<<4)|pxl
// converts channels g*8..g*8+8 of px pxl -> the packed P words ARE the MFMA
// A-fragment for that lane (fragment layout: lane L holds px L&15, channels
// (L>>4)*8..+8). A never touches LDS; no barriers anywhere in main.
// R3's failure modes fixed: 8 independent kg acc chains (4-kg interleave),
// B loaded in 4-kg quads (12 loads ahead of 24 MFMAs), acc 32 regs ->
// peak ~115 regs, 4 blocks/CU, 2048 blocks = 2 uniform residency rounds.
// Numerics bit-identical to proven kernels: same split3t + perm packing,
// same A/B operand bytes, per-acc term order (0,0)(0,1)(0,2)(1,0)(1,1)(2,0)
// over ascending chunks, R3-proven B addressing + epilogue argmin, x2 chain
// reproduced in old (h0 ch 0-15, h1 ch 16-31) order via lane ping-pong,
// R5-proven fused histogram.
__global__ __launch_bounds__(256, 4) void main_kernel(
    const float* __restrict__ x, const unsigned short* __restrict__ Bt,
    const float* __restrict__ c2v, float* __restrict__ out) {

    __shared__ float x2w[4][16];     // per-wave x2 bounce (wave-local only)

    const int t    = threadIdx.x;
    const int lane = t & 63;
    const int w    = t >> 6;
    const int l15  = lane & 15;      // px within wave tile / k within group
    const int g    = lane >> 4;      // channel group (8 ch) / row quad

    const int gw  = blockIdx.x * 4 + w;     // global wave id, 0..8191
    const int img = gw >> 8;                // 256 waves per image
    const int pxb = (gw & 255) * 16;        // px base within image

    const float* xg = x + (size_t)img * (C_DIM * PIX) + pxb + l15;
    const unsigned short* btv = Bt + l15 * 768 + g * 8;

    f32x4 acc[8];
#pragma unroll
    for (int kg = 0; kg < 8; ++kg) acc[kg] = (f32x4){0.f, 0.f, 0.f, 0.f};

    float xr[8];
#pragma unroll
    for (int j = 0; j < 8; ++j) xr[j] = xg[(size_t)(g * 8 + j) * PIX];

    float x2r = 0.f;   // running x2 chain (valid on even-g lanes at chunk start)

#pragma unroll 1
    for (int ci = 0; ci < 8; ++ci) {
        // ---- convert xr -> A-fragments in REGISTERS (trunc split + perm) ----
        unsigned P0[4], P1[4], P2[4];
#pragma unroll
        for (int jj = 0; jj < 4; ++jj) {
            float v0 = xr[jj * 2], v1 = xr[jj * 2 + 1];
            unsigned h0, m0, l0, h1, m1, l1;
            split3t(v0, h0, m0, l0);
            split3t(v1, h1, m1, l1);
            // bytes [h0.b2,h0.b3,h1.b2,h1.b3] == (h0>>16)|(h1&0xffff0000)
            P0[jj] = __builtin_amdgcn_perm(h1, h0, 0x07060302u);
            P1[jj] = __builtin_amdgcn_perm(m1, m0, 0x07060302u);
            P2[jj] = __builtin_amdgcn_perm(l1, l0, 0x07060302u);
        }
        union { uint4 u; short8 s; } A0, A1, A2;
        A0.u = make_uint4(P0[0], P0[1], P0[2], P0[3]);
        A1.u = make_uint4(P1[0], P1[1], P1[2], P1[3]);
        A2.u = make_uint4(P2[0], P2[1], P2[2], P2[3]);
        short8 af[3] = {A0.s, A1.s, A2.s};

        // ---- exact x2 chain, old order: per chunk, even-g lane chains its 8
        // (ch ..+0..7), passes to odd-g lane which chains ch ..+8..15; the
        // running value ping-pongs back. Identical fmaf sequence to proven
        // x2p[h] chains (ci ascending, ch ascending within half).
        float tA = x2r;
#pragma unroll
        for (int j = 0; j < 8; ++j) tA = fmaf(xr[j], xr[j], tA);
        float ux = __shfl_xor(tA, 16);
        float tB = ux;
#pragma unroll
        for (int j = 0; j < 8; ++j) tB = fmaf(xr[j], xr[j], tB);
        x2r = __shfl_xor(tB, 16);

        // ---- prefetch next x chunk (compiler-counted vmcnt keeps it in
        // flight past the B-quad waits) ----
        if (ci < 7) {
#pragma unroll
            for (int j = 0; j < 8; ++j)
                xr[j] = xg[(size_t)((ci + 1) * 32 + g * 8 + j) * PIX];
        }

        // ---- 2 quads of 4 k-groups: 12 B loads then 24 MFMAs (4 indep
        // acc chains); per-acc pair order (0,0)(0,1)(0,2)(1,0)(1,1)(2,0).
#pragma unroll
        for (int kq = 0; kq < 2; ++kq) {
            short8 bq[4][3];
#pragma unroll
            for (int kk = 0; kk < 4; ++kk)
#pragma unroll
                for (int p = 0; p < 3; ++p)
                    bq[kk][p] = *(const short8*)(btv + (kq * 4 + kk) * 12288 +
                                                 p * 256 + ci * 32);
            __builtin_amdgcn_s_setprio(1);
#pragma unroll
            for (int pa = 0; pa < 3; ++pa)
#pragma unroll
                for (int pb2 = 0; pb2 < 3; ++pb2) {
                    if (pb2 < 3 - pa) {
#pragma unroll
                        for (int kk = 0; kk < 4; ++kk)
                            acc[kq * 4 + kk] = __builtin_amdgcn_mfma_f32_16x16x32_bf16(
                                af[pa], bq[kk][pb2], acc[kq * 4 + kk], 0, 0, 0);
                    }
                }
            __builtin_amdgcn_s_setprio(0);
        }
    }

    // ---- x2 finalize: even-g lanes hold completed half-sums; combine in
    // proven order S_h0 + S_h1 and bounce via wave-private LDS.
    {
        float x2o = __shfl_xor(x2r, 32);
        if (g == 0) x2w[w][l15] = x2r + x2o;
    }

    // ---- epilogue: dist + argmin (R3-proven exact) + fused histogram ----
    float c2r[8];
#pragma unroll
    for (int kg = 0; kg < 8; ++kg) c2r[kg] = c2v[kg * 16 + l15];

    const size_t ob = (size_t)img * (64 * (K_DIM + 1));

#pragma unroll
    for (int r = 0; r < 4; ++r) {
        float x2v = x2w[w][g * 4 + r];           // wave-local broadcast read
        unsigned long long best = 0xFFFFFFFFFFFFFFFFull;
#pragma unroll
        for (int kg = 0; kg < 8; ++kg) {
            float d = (x2v - 2.0f * acc[kg][r]) + c2r[kg];
            unsigned long long key =
                ((unsigned long long)mono(d) << 32) | (unsigned)(kg * 16 + l15);
            best = umin64(best, key);
        }
        best = umin64(best, __shfl_xor(best, 1));
        best = umin64(best, __shfl_xor(best, 2));
        best = umin64(best, __shfl_xor(best, 4));
        best = umin64(best, __shfl_xor(best, 8));
        if (l15 == 0) {
            int c  = (int)(best & 0xFFu);
            int p  = pxb + g * 4 + r;            // pixel index in image
            int sy = (p >> 6) >> 3;              // row / 8
            int sx = (p & 63) >> 3;              // col / 8
            atomicAdd(&out[ob + (sy * 8 + sx) * (K_DIM + 1) + c + 1],
                      0.015625f);                // 1/64 (exact dyadic sums)
        }
    }
}

extern "C" void kernel_launch(void* const* d_in, const int* in_sizes, int n_in,
                              void* d_out, int out_size, void* d_ws, size_t ws_size,
                              hipStream_t stream) {
    const float* x  = (const float*)d_in[0];       // (32, 256, 64, 64) fp32
    const float* cl = (const float*)d_in[1];       // (128, 256) fp32
    float* out = (float*)d_out;                    // (32, 64, 129) fp32

    unsigned short* Bt = (unsigned short*)d_ws;                  // 196608 B
    float* c2 = (float*)((char*)d_ws + 196608);                  // 512 B

    hipMemsetAsync(d_out, 0, (size_t)out_size, stream);
    prep_kernel<<<K_DIM, 64, 0, stream>>>(cl, Bt, c2);
    main_kernel<<<(N_IMG * PIX) / 64, 256, 0, stream>>>(x, Bt, c2, out);
}

// Round 7
// 228.608 us; speedup vs baseline: 1.4980x; 1.4980x over previous
//
#include <hip/hip_runtime.h>

#define C_DIM 256
#define K_DIM 128
#define HW_DIM 64
#define PIX 4096
#define N_IMG 32

using short8 = __attribute__((ext_vector_type(8))) short;
using f32x4  = __attribute__((ext_vector_type(4))) float;

// CK-style barrier: waits own LDS ops (lgkmcnt) only — leaves global-load
// prefetches (vmcnt) in flight across the barrier, unlike __syncthreads().
__device__ __forceinline__ void lds_barrier() {
    asm volatile("s_waitcnt lgkmcnt(0)\n\ts_barrier" ::: "memory");
}

__device__ __forceinline__ unsigned long long umin64(unsigned long long a, unsigned long long b) {
    return a < b ? a : b;
}
__device__ __forceinline__ unsigned mono(float d) {
    unsigned u = __float_as_uint(d);
    return u ^ ((u & 0x80000000u) ? 0xFFFFFFFFu : 0x80000000u);
}

// Truncation split: v = hi + mid + lo, each term = top-16-bit bitmask value
// (exact Sterbenz residuals; lo ~ 2^-16 * v). Cheap: and/sub only.
__device__ __forceinline__ void split3t(float v, unsigned& hu, unsigned& mu, unsigned& lu) {
    unsigned u = __float_as_uint(v);
    unsigned hf = u & 0xffff0000u;
    float r1 = v - __uint_as_float(hf);
    unsigned r1u = __float_as_uint(r1);
    unsigned mf = r1u & 0xffff0000u;
    float r2 = r1 - __uint_as_float(mf);
    hu = u; mu = r1u; lu = __float_as_uint(r2);   // consumers take >>16
}

// P: per cluster k: trunc 3-way split -> Bt[k][768] (planes hi/mid/lo) + exact c2
__global__ __launch_bounds__(64) void prep_kernel(const float* __restrict__ cl,
                                                  unsigned short* __restrict__ Bt,
                                                  float* __restrict__ c2) {
    int k = blockIdx.x;
    int lane = threadIdx.x;
    const float4* row = (const float4*)(cl + k * C_DIM);
    float4 v = row[lane];
    float vv[4] = {v.x, v.y, v.z, v.w};
    unsigned short* bk = Bt + k * 768 + lane * 4;
#pragma unroll
    for (int i = 0; i < 4; ++i) {
        unsigned hu, mu, lu;
        split3t(vv[i], hu, mu, lu);
        bk[i]       = (unsigned short)(hu >> 16);
        bk[256 + i] = (unsigned short)(mu >> 16);
        bk[512 + i] = (unsigned short)(lu >> 16);
    }
    if (lane == 0) {   // identical op order to proven-exact c2
        float s = 0.f;
#pragma unroll
        for (int i = 0; i < C_DIM / 4; ++i) {
            float4 u = row[i];
            s = fmaf(u.x, u.x, s);
            s = fmaf(u.y, u.y, s);
            s = fmaf(u.z, u.z, s);
            s = fmaf(u.w, u.w, s);
        }
        c2[k] = s;
    }
}

// Main, ROUND-NEW: 64-px tile + DOUBLE-BUFFERED A-tile -> ONE barrier/chunk.
// Keeps R5's proven wave-role split (4 waves own 32-k slices, B in 6 regs
// reused x32, A shared via LDS) — the structure wave-private variants broke.
// Per iter ci: [bv(ci) loads] [convert chunk ci+1 -> buf nxt] [prefetch
// xr ci+2] [MFMA chunk ci from buf cur] [barrier]. Convert runs a full
// iteration ahead of its consumer; buffers disjoint -> single barrier.
// LDS 2x12.3 KB ~= R5's 24.6 KB -> 4 blocks/CU kept; acc halves to 32 regs
// giving slack to hoist bv before convert (L2 latency covered).
// Numerics bit-identical: same split3t+perm convert bytes, same per-acc
// (pa,pb) order (0,0)(0,1)(0,2)(1,0)(1,1)(2,0) over ascending ci, same B
// addressing, R6-proven x2 ping-pong (order S_h0+S_h1), R5-proven argmin
// (unique keys) + fused histogram (exact dyadic 1/64 sums).
__global__ __launch_bounds__(256, 4) void main_kernel(
    const float* __restrict__ x, const unsigned short* __restrict__ Bt,
    const float* __restrict__ c2v, float* __restrict__ out) {

    __shared__ __align__(16) unsigned short Ap[2][6144];   // 2 x 12288 B
    __shared__ float x2sh[64];
    unsigned long long* red = (unsigned long long*)&Ap[0][0];  // epilogue alias

    const int t    = threadIdx.x;
    const int lane = t & 63;
    const int w    = t >> 6;
    const int l15  = lane & 15;    // px within 16-row group / k within group
    const int g    = lane >> 4;    // ch-group (8 ch) on convert; k-quad on B/epi

    const int gb  = blockIdx.x;          // 2048 blocks
    const int img = gb >> 6;             // 64 blocks per image
    const int pb  = (gb & 63) * 64;      // px base = image row * 64

    // converter: this thread owns px = pb + w*16 + l15, channels g*8..g*8+7
    const float* xg = x + (size_t)img * (C_DIM * PIX) + pb + w * 16 + l15;
    const unsigned short* btb = Bt + (w * 32 + l15) * 768 + g * 8;

    f32x4 acc[4][2];
#pragma unroll
    for (int m = 0; m < 4; ++m)
#pragma unroll
        for (int ns = 0; ns < 2; ++ns) acc[m][ns] = (f32x4){0.f, 0.f, 0.f, 0.f};

    float xr[8];
#pragma unroll
    for (int j = 0; j < 8; ++j) xr[j] = xg[(size_t)(g * 8 + j) * PIX];

    float x2r = 0.f;
    // convert write base (ushort idx): wave w owns m-tile w; lane-linear 16B
    const int wbase = w * 512 + g * 128 + l15 * 8;

    // ---- convert one chunk (xr) into buffer dst + x2 chain step.
    // Chain order == proven: chainA (ch 0-15/chunk) on g0<->g1, chainB
    // (ch 16-31) on g2<->g3, both ci-major j-minor (R6-proven ping-pong).
#define CONVERT_CHUNK(dst)                                                    \
    {                                                                         \
        unsigned P0[4], P1[4], P2[4];                                         \
        _Pragma("unroll")                                                     \
        for (int jj = 0; jj < 4; ++jj) {                                      \
            float v0 = xr[jj * 2], v1 = xr[jj * 2 + 1];                       \
            unsigned h0, m0, l0, h1, m1, l1;                                  \
            split3t(v0, h0, m0, l0);                                          \
            split3t(v1, h1, m1, l1);                                          \
            P0[jj] = __builtin_amdgcn_perm(h1, h0, 0x07060302u);              \
            P1[jj] = __builtin_amdgcn_perm(m1, m0, 0x07060302u);              \
            P2[jj] = __builtin_amdgcn_perm(l1, l0, 0x07060302u);              \
        }                                                                     \
        *(uint4*)&(dst)[wbase]        = make_uint4(P0[0], P0[1], P0[2], P0[3]);\
        *(uint4*)&(dst)[2048 + wbase] = make_uint4(P1[0], P1[1], P1[2], P1[3]);\
        *(uint4*)&(dst)[4096 + wbase] = make_uint4(P2[0], P2[1], P2[2], P2[3]);\
        float tA = x2r;                                                       \
        _Pragma("unroll")                                                     \
        for (int j = 0; j < 8; ++j) tA = fmaf(xr[j], xr[j], tA);              \
        float ux = __shfl_xor(tA, 16);                                        \
        float tB = ux;                                                        \
        _Pragma("unroll")                                                     \
        for (int j = 0; j < 8; ++j) tB = fmaf(xr[j], xr[j], tB);              \
        x2r = __shfl_xor(tB, 16);                                             \
    }

    // ---- prologue: chunk 0 -> buf0; prefetch chunk 1 ----
    CONVERT_CHUNK(Ap[0])
#pragma unroll
    for (int j = 0; j < 8; ++j) xr[j] = xg[(size_t)(32 + g * 8 + j) * PIX];
    lds_barrier();

#pragma unroll 1
    for (int ci = 0; ci < 8; ++ci) {
        // B-fragments first: consumed by MFMA after convert (~full convert
        // of latency cover); xr prefetch issued behind them keeps the vmcnt
        // FIFO ordering (MFMA waits bv at vmcnt(8), xr stays in flight).
        short8 bv[3][2];
#pragma unroll
        for (int p = 0; p < 3; ++p) {
            bv[p][0] = *(const short8*)(btb + p * 256 + ci * 32);
            bv[p][1] = *(const short8*)(btb + 16 * 768 + p * 256 + ci * 32);
        }

        // convert chunk ci+1 into the buffer MFMA is NOT reading
        if (ci < 7) CONVERT_CHUNK(Ap[(ci + 1) & 1])

        // prefetch chunk ci+2 (consumed by next iteration's convert)
        if (ci < 6) {
#pragma unroll
            for (int j = 0; j < 8; ++j)
                xr[j] = xg[(size_t)((ci + 2) * 32 + g * 8 + j) * PIX];
        }

        // MFMA chunk ci from current buffer; per-acc term order = pa asc,
        // pb asc (identical to proven kernels).
        const unsigned short* ap = &Ap[ci & 1][0];
        __builtin_amdgcn_s_setprio(1);
#pragma unroll
        for (int pa = 0; pa < 3; ++pa) {
#pragma unroll
            for (int m = 0; m < 4; ++m) {
                short8 af = *(const short8*)&ap[pa * 2048 + m * 512 + lane * 8];
#pragma unroll
                for (int pb2 = 0; pb2 < 3; ++pb2) {
                    if (pb2 < 3 - pa) {
                        acc[m][0] = __builtin_amdgcn_mfma_f32_16x16x32_bf16(af, bv[pb2][0], acc[m][0], 0, 0, 0);
                        acc[m][1] = __builtin_amdgcn_mfma_f32_16x16x32_bf16(af, bv[pb2][1], acc[m][1], 0, 0, 0);
                    }
                }
            }
        }
        __builtin_amdgcn_s_setprio(0);

        // one barrier per chunk: drains my af reads of cur + writes of nxt;
        // after it, nxt is visible to all and cur is safely recyclable.
        if (ci < 7) lds_barrier();
    }

    // ---- x2 finalize: combine chainA + chainB in proven order ----
    {
        float x2o = __shfl_xor(x2r, 32);
        if (g == 0) x2sh[w * 16 + l15] = x2r + x2o;
    }
    lds_barrier();   // x2sh cross-wave visible; also drains last af reads

    // ---- epilogue: dist = (x2 - 2*S) + c2, argmin (proven exact) ----
    const float c2a0 = c2v[w * 32 + l15];
    const float c2a1 = c2v[w * 32 + 16 + l15];
    const unsigned n0 = (unsigned)(w * 32 + l15);
    const unsigned n1 = n0 + 16;

#pragma unroll
    for (int m = 0; m < 4; ++m) {
#pragma unroll
        for (int r = 0; r < 4; ++r) {
            int pxl = m * 16 + g * 4 + r;             // C/D: row = quad*4 + reg
            float x2v = x2sh[pxl];
            float d0 = (x2v - 2.0f * acc[m][0][r]) + c2a0;
            float d1 = (x2v - 2.0f * acc[m][1][r]) + c2a1;
            unsigned long long k0 = ((unsigned long long)mono(d0) << 32) | n0;
            unsigned long long k1 = ((unsigned long long)mono(d1) << 32) | n1;
            unsigned long long best = umin64(k0, k1);
            best = umin64(best, __shfl_xor(best, 1));
            best = umin64(best, __shfl_xor(best, 2));
            best = umin64(best, __shfl_xor(best, 4));
            best = umin64(best, __shfl_xor(best, 8));
            if (l15 == 0) red[w * 64 + pxl] = best;
        }
    }
    lds_barrier();

    // ---- fused histogram (R5-proven): block covers one image row ----
    if (t < 64) {
        unsigned long long m0 = umin64(umin64(red[t], red[64 + t]),
                                       umin64(red[128 + t], red[192 + t]));
        int c  = (int)(m0 & 0xFFu);
        int sy = (gb & 63) >> 3;           // image row / 8
        int sx = t >> 3;                   // col / 8
        atomicAdd(&out[(size_t)img * (64 * (K_DIM + 1)) +
                       (sy * 8 + sx) * (K_DIM + 1) + c + 1],
                  0.015625f);              // 1/64 (exact dyadic sums)
    }
#undef CONVERT_CHUNK
}

extern "C" void kernel_launch(void* const* d_in, const int* in_sizes, int n_in,
                              void* d_out, int out_size, void* d_ws, size_t ws_size,
                              hipStream_t stream) {
    const float* x  = (const float*)d_in[0];       // (32, 256, 64, 64) fp32
    const float* cl = (const float*)d_in[1];       // (128, 256) fp32
    float* out = (float*)d_out;                    // (32, 64, 129) fp32

    unsigned short* Bt = (unsigned short*)d_ws;                  // 196608 B
    float* c2 = (float*)((char*)d_ws + 196608);                  // 512 B

    hipMemsetAsync(d_out, 0, (size_t)out_size, stream);
    prep_kernel<<<K_DIM, 64, 0, stream>>>(cl, Bt, c2);
    main_kernel<<<(N_IMG * PIX) / 64, 256, 0, stream>>>(x, Bt, c2, out);
}

// Round 8
// 214.256 us; speedup vs baseline: 1.5984x; 1.0670x over previous
//
#include <hip/hip_runtime.h>

#define C_DIM 256
#define K_DIM 128
#define HW_DIM 64
#define PIX 4096
#define N_IMG 32

using short8 = __attribute__((ext_vector_type(8))) short;
using f32x4  = __attribute__((ext_vector_type(4))) float;

// CK-style barrier: waits own LDS ops (lgkmcnt) only — leaves global-load
// prefetches (vmcnt) in flight across the barrier, unlike __syncthreads().
__device__ __forceinline__ void lds_barrier() {
    asm volatile("s_waitcnt lgkmcnt(0)\n\ts_barrier" ::: "memory");
}

__device__ __forceinline__ unsigned long long umin64(unsigned long long a, unsigned long long b) {
    return a < b ? a : b;
}
__device__ __forceinline__ unsigned mono(float d) {
    unsigned u = __float_as_uint(d);
    return u ^ ((u & 0x80000000u) ? 0xFFFFFFFFu : 0x80000000u);
}

// Truncation split: v = hi + mid + lo, each term = top-16-bit bitmask value
// (exact Sterbenz residuals; lo ~ 2^-16 * v). Cheap: and/sub only.
__device__ __forceinline__ void split3t(float v, unsigned& hu, unsigned& mu, unsigned& lu) {
    unsigned u = __float_as_uint(v);
    unsigned hf = u & 0xffff0000u;
    float r1 = v - __uint_as_float(hf);
    unsigned r1u = __float_as_uint(r1);
    unsigned mf = r1u & 0xffff0000u;
    float r2 = r1 - __uint_as_float(mf);
    hu = u; mu = r1u; lu = __float_as_uint(r2);   // consumers take >>16
}

// P: per cluster k: trunc 3-way split -> Bt[k][768] (planes hi/mid/lo) + exact c2
__global__ __launch_bounds__(64) void prep_kernel(const float* __restrict__ cl,
                                                  unsigned short* __restrict__ Bt,
                                                  float* __restrict__ c2) {
    int k = blockIdx.x;
    int lane = threadIdx.x;
    const float4* row = (const float4*)(cl + k * C_DIM);
    float4 v = row[lane];
    float vv[4] = {v.x, v.y, v.z, v.w};
    unsigned short* bk = Bt + k * 768 + lane * 4;
#pragma unroll
    for (int i = 0; i < 4; ++i) {
        unsigned hu, mu, lu;
        split3t(vv[i], hu, mu, lu);
        bk[i]       = (unsigned short)(hu >> 16);
        bk[256 + i] = (unsigned short)(mu >> 16);
        bk[512 + i] = (unsigned short)(lu >> 16);
    }
    if (lane == 0) {   // identical op order to proven-exact c2
        float s = 0.f;
#pragma unroll
        for (int i = 0; i < C_DIM / 4; ++i) {
            float4 u = row[i];
            s = fmaf(u.x, u.x, s);
            s = fmaf(u.y, u.y, s);
            s = fmaf(u.z, u.z, s);
            s = fmaf(u.w, u.w, s);
        }
        c2[k] = s;
    }
}

// Main: proven round-5 best (214.7 us total), dead code cleaned.
// Block = 256 thr (4 waves), S[128px][128k] via 16x16x32 bf16 MFMA, 6
// cross-term pairs; per-acc term order (0,0)(0,1)(0,2)(1,0)(1,1)(2,0) over
// ascending chunks. 4 blocks/CU via __launch_bounds__(256,4) — grid 1024 =
// 256 CU x 4, single uniform residency round. bv loads sit after convert
// (short live range under the 128-reg cap) and before the xr prefetch
// (vmcnt FIFO: first MFMA waits vmcnt(16), xr prefetch stays in flight
// across both barriers). v_perm packing; s_setprio(1) around MFMA phase;
// histogram fused into the epilogue (exact dyadic 1/64 atomic sums).
// Structural rewrites (dbuf/k-split/reg-direct/64px-dbuf) went 0-for-4 —
// this simple 2-barrier loop is the measured optimum (~736 TF effective,
// ~84% of the m97-class plain-HIP GEMM reference, with convert/x2/argmin/
// hist fused in).
__global__ __launch_bounds__(256, 4) void main_kernel(
    const float* __restrict__ x, const unsigned short* __restrict__ Bt,
    const float* __restrict__ c2v, float* __restrict__ out) {

    __shared__ __align__(16) unsigned short Ap[3 * 4096];   // 24576 B
    __shared__ float x2p[2][128];                           // 1024 B
    unsigned long long* red = (unsigned long long*)Ap;      // aliased (epilogue only)

    const int t    = threadIdx.x;
    const int lane = t & 63;
    const int w    = t >> 6;
    const int q    = lane >> 4;
    const int l15  = lane & 15;

    const int px = t & 127;        // conversion: this thread's pixel row
    const int h  = t >> 7;         // conversion: c-half (0: c 0-15, 1: c 16-31)

    const int b   = blockIdx.x;
    const int img = b >> 5;
    const int pb  = (b & 31) * 128;

    const float* xg = x + (size_t)img * (C_DIM * PIX) + pb + px;

    f32x4 acc[8][2];
#pragma unroll
    for (int m = 0; m < 8; ++m)
#pragma unroll
        for (int ns = 0; ns < 2; ++ns) acc[m][ns] = (f32x4){0.f, 0.f, 0.f, 0.f};

    float xr[16];
#pragma unroll
    for (int j = 0; j < 16; ++j) xr[j] = xg[(size_t)(h * 16 + j) * PIX];

    float x2part = 0.f;
    const unsigned short* btb = Bt + (w * 32 + l15) * 768 + q * 8;

    // convert-phase LDS write base (ushort idx within a plane)
    const int wbase = (px >> 4) * 512 + (px & 15) * 8 + h * 2 * 128;

#pragma unroll 1
    for (int ci = 0; ci < 8; ++ci) {
        // ---- convert xr -> 3 bf16 planes in LDS (trunc split + perm) + x2 ----
#pragma unroll
        for (int g = 0; g < 2; ++g) {
            unsigned p0[4], p1[4], p2[4];
#pragma unroll
            for (int jj = 0; jj < 4; ++jj) {
                float v0 = xr[g * 8 + jj * 2], v1 = xr[g * 8 + jj * 2 + 1];
                unsigned h0, m0, l0, h1, m1, l1;
                split3t(v0, h0, m0, l0);
                split3t(v1, h1, m1, l1);
                // bytes [h0.b2,h0.b3,h1.b2,h1.b3] == (h0>>16)|(h1&0xffff0000)
                p0[jj] = __builtin_amdgcn_perm(h1, h0, 0x07060302u);
                p1[jj] = __builtin_amdgcn_perm(m1, m0, 0x07060302u);
                p2[jj] = __builtin_amdgcn_perm(l1, l0, 0x07060302u);
                x2part = fmaf(v0, v0, x2part);
                x2part = fmaf(v1, v1, x2part);
            }
            int base = wbase + g * 128;   // (q = h*2+g) * 16 lanes * 8 ushorts
            *(uint4*)&Ap[base]            = make_uint4(p0[0], p0[1], p0[2], p0[3]);
            *(uint4*)&Ap[4096 + base]     = make_uint4(p1[0], p1[1], p1[2], p1[3]);
            *(uint4*)&Ap[8192 + base]     = make_uint4(p2[0], p2[1], p2[2], p2[3]);
        }
        if (ci == 7) x2p[h][px] = x2part;

        // ---- B-fragments: 6 unique (plane x n-half), L2-hot, imm-folded
        // addressing. Issued AFTER convert (short live range) but BEFORE the
        // xr prefetch (vmcnt FIFO keeps xr in flight past the MFMA's bv wait).
        short8 bv[3][2];
#pragma unroll
        for (int p = 0; p < 3; ++p) {
            bv[p][0] = *(const short8*)(btb + p * 256 + ci * 32);
            bv[p][1] = *(const short8*)(btb + 16 * 768 + p * 256 + ci * 32);
        }

        // ---- prefetch next x chunk (vmcnt survives the barriers below) ----
        if (ci < 7) {
#pragma unroll
            for (int j = 0; j < 16; ++j)
                xr[j] = xg[(size_t)((ci + 1) * 32 + h * 16 + j) * PIX];
        }

        lds_barrier();   // Ap ready (LDS-only wait)

        // ---- MFMA: pa outer, m-pairs, pb inner; per-acc term order =
        // pa ascending then pb ascending (identical to proven rounds).
        __builtin_amdgcn_s_setprio(1);
#pragma unroll
        for (int pa = 0; pa < 3; ++pa) {
#pragma unroll
            for (int mg = 0; mg < 4; ++mg) {
                const int m0 = mg * 2, m1 = mg * 2 + 1;
                short8 af0 = *(const short8*)&Ap[pa * 4096 + m0 * 512 + lane * 8];
                short8 af1 = *(const short8*)&Ap[pa * 4096 + m1 * 512 + lane * 8];
#pragma unroll
                for (int pb2 = 0; pb2 < 3; ++pb2) {
                    if (pb2 < 3 - pa) {
                        acc[m0][0] = __builtin_amdgcn_mfma_f32_16x16x32_bf16(af0, bv[pb2][0], acc[m0][0], 0, 0, 0);
                        acc[m0][1] = __builtin_amdgcn_mfma_f32_16x16x32_bf16(af0, bv[pb2][1], acc[m0][1], 0, 0, 0);
                        acc[m1][0] = __builtin_amdgcn_mfma_f32_16x16x32_bf16(af1, bv[pb2][0], acc[m1][0], 0, 0, 0);
                        acc[m1][1] = __builtin_amdgcn_mfma_f32_16x16x32_bf16(af1, bv[pb2][1], acc[m1][1], 0, 0, 0);
                    }
                }
            }
        }
        __builtin_amdgcn_s_setprio(0);
        lds_barrier();   // all Ap reads done before next convert overwrites
    }

    // ---- epilogue: dist = (x2 - 2*S) + c2, argmin (proven exact) ----
    const float c2a0 = c2v[w * 32 + l15];
    const float c2a1 = c2v[w * 32 + 16 + l15];
    const unsigned n0 = (unsigned)(w * 32 + l15);
    const unsigned n1 = n0 + 16;

#pragma unroll
    for (int m = 0; m < 8; ++m) {
#pragma unroll
        for (int r = 0; r < 4; ++r) {
            int pxl = m * 16 + q * 4 + r;             // C/D: row = quad*4 + reg
            float x2v = x2p[0][pxl] + x2p[1][pxl];
            float d0 = (x2v - 2.0f * acc[m][0][r]) + c2a0;
            float d1 = (x2v - 2.0f * acc[m][1][r]) + c2a1;
            unsigned long long k0 = ((unsigned long long)mono(d0) << 32) | n0;
            unsigned long long k1 = ((unsigned long long)mono(d1) << 32) | n1;
            unsigned long long best = umin64(k0, k1);
            best = umin64(best, __shfl_xor(best, 1));
            best = umin64(best, __shfl_xor(best, 2));
            best = umin64(best, __shfl_xor(best, 4));
            best = umin64(best, __shfl_xor(best, 8));
            if (l15 == 0) red[w * 128 + pxl] = best;
        }
    }
    lds_barrier();

    // ---- fused histogram: each t<128 owns pixel px=pb+t, adds 1/64 to its
    // (tile, code+1) cell. out zeroed by memsetAsync; k/64 sums are exact
    // fp32 dyadics -> order-independent, bitwise == count/64.
    if (t < 128) {
        unsigned long long m0 = umin64(umin64(red[t], red[128 + t]),
                                       umin64(red[256 + t], red[384 + t]));
        int c = (int)(m0 & 0xFFu);
        int p = pb + t;                    // pixel index in image
        int sy = (p >> 6) >> 3;            // row / 8
        int sx = (p & 63) >> 3;            // col / 8
        atomicAdd(&out[(size_t)img * (64 * (K_DIM + 1)) +
                       (sy * 8 + sx) * (K_DIM + 1) + c + 1],
                  0.015625f);              // 1/64
    }
}

extern "C" void kernel_launch(void* const* d_in, const int* in_sizes, int n_in,
                              void* d_out, int out_size, void* d_ws, size_t ws_size,
                              hipStream_t stream) {
    const float* x  = (const float*)d_in[0];       // (32, 256, 64, 64) fp32
    const float* cl = (const float*)d_in[1];       // (128, 256) fp32
    float* out = (float*)d_out;                    // (32, 64, 129) fp32

    unsigned short* Bt = (unsigned short*)d_ws;                  // 196608 B
    float* c2 = (float*)((char*)d_ws + 196608);                  // 512 B

    hipMemsetAsync(d_out, 0, (size_t)out_size, stream);
    prep_kernel<<<K_DIM, 64, 0, stream>>>(cl, Bt, c2);
    main_kernel<<<(N_IMG * PIX) / 128, 256, 0, stream>>>(x, Bt, c2, out);
}